// Round 5
// baseline (481.306 us; speedup 1.0000x reference)
//
#include <hip/hip_runtime.h>
#include <hip/hip_bf16.h>
#include <math.h>

using bf16 = __hip_bfloat16;
typedef __attribute__((ext_vector_type(8))) short bf16x8;  // 8 bf16 = 4 VGPRs
typedef __attribute__((ext_vector_type(4))) short bf16x4;  // 4 bf16 = 2 VGPRs
typedef __attribute__((ext_vector_type(4))) float f32x4;

#define GLOBAL_AS __attribute__((address_space(1)))
#define LDS_AS __attribute__((address_space(3)))

__device__ __forceinline__ float b2f(bf16 v) { return __bfloat162float(v); }
__device__ __forceinline__ bf16 f2b(float v) { return __float2bfloat16(v); }
__device__ __forceinline__ float bs2f(short s) {
  union { unsigned u; float f; } x;
  x.u = ((unsigned)(unsigned short)s) << 16;
  return x.f;
}

// Fast GELU (tanh form via hw exp): |err| vs erf-GELU <= ~2e-4 absolute.
__device__ __forceinline__ float gelu_f(float x) {
  float u = x * (0.7978845608f + 0.0356774081f * x * x);
  float t = 1.0f - 2.0f / (1.0f + __expf(2.0f * u));
  return 0.5f * x * (1.0f + t);
}

// ---------------------------------------------------------------------------
// Fused f32->bf16 conversion for x, Wq, Wk, Wv. 4 elem/thread.
// blocks: x 8192 | Wq 1024 | Wk 1024 | Wv 1024  (grid 11264)
// ---------------------------------------------------------------------------
__global__ __launch_bounds__(256) void k_conv4(
    const float* __restrict__ x, const float* __restrict__ Wq,
    const float* __restrict__ Wk, const float* __restrict__ Wv,
    bf16* __restrict__ xb, bf16* __restrict__ Wqb,
    bf16* __restrict__ Wkb, bf16* __restrict__ Wvb) {
  int bid = blockIdx.x;
  const float* src;
  bf16* dst;
  int local;
  if (bid < 8192) { src = x; dst = xb; local = bid; }
  else {
    int b2 = bid - 8192;
    int w = b2 >> 10;
    local = b2 & 1023;
    src = (w == 0) ? Wq : (w == 1) ? Wk : Wv;
    dst = (w == 0) ? Wqb : (w == 1) ? Wkb : Wvb;
  }
  int i = local * 256 + threadIdx.x;
  float4 v = ((const float4*)src)[i];
  bf16 t[4] = {f2b(v.x), f2b(v.y), f2b(v.z), f2b(v.w)};
  *(bf16x4*)(dst + 4 * (size_t)i) = *(bf16x4*)t;
}

// Fused conversion for Wo (1024 blocks) + Wf (4096 blocks). grid 5120.
__global__ __launch_bounds__(256) void k_conv2(
    const float* __restrict__ Wo, const float* __restrict__ Wf,
    bf16* __restrict__ Wob, bf16* __restrict__ Wfb) {
  int bid = blockIdx.x;
  const float* src = (bid < 1024) ? Wo : Wf;
  bf16* dst = (bid < 1024) ? Wob : Wfb;
  int local = (bid < 1024) ? bid : bid - 1024;
  int i = local * 256 + threadIdx.x;
  float4 v = ((const float4*)src)[i];
  bf16 t[4] = {f2b(v.x), f2b(v.y), f2b(v.z), f2b(v.w)};
  *(bf16x4*)(dst + 4 * (size_t)i) = *(bf16x4*)t;
}

// ===========================================================================
// OLD ENGINE (m97 structure, 128x128 tile, 256 threads) — kept for k_v /
// k_attn / k_out where 256^2 tiles would under-fill the grid.
// ===========================================================================
__device__ __forceinline__ void stage_async(const bf16* __restrict__ g,
                                            int ldg, bf16* __restrict__ s) {
  int lane = threadIdx.x & 63;
  int wave = threadIdx.x >> 6;
  bf16* lds = s + wave * 1024;  // 2048 B per wave chunk
  const bf16* g0 = g + (size_t)(wave * 32 + (lane >> 2)) * ldg + ((lane & 3) << 3);
  const bf16* g1 = g0 + (size_t)16 * ldg;
  __builtin_amdgcn_global_load_lds((GLOBAL_AS const unsigned*)g0,
                                   (LDS_AS unsigned*)lds, 16, 0, 0);
  __builtin_amdgcn_global_load_lds((GLOBAL_AS const unsigned*)g1,
                                   (LDS_AS unsigned*)(lds + 512), 16, 0, 0);
}

struct Acc { f32x4 a[4][4]; };

__device__ __forceinline__ void gemm_core(const bf16* __restrict__ A,
                                          const bf16* __restrict__ B,
                                          int K, int lda, int ldb, Acc& acc,
                                          bf16* sA, bf16* sB) {
  int lane = threadIdx.x & 63;
  int wave = threadIdx.x >> 6;
  int wm = wave & 1, wn = wave >> 1;
  int r = lane & 15;            // operand row: m (or n) = lane&15
  int ko = (lane >> 4) << 3;    // k offset = (lane>>4)*8

  for (int k0 = 0; k0 < K; k0 += 32) {
    stage_async(A + k0, lda, sA);
    stage_async(B + k0, ldb, sB);
    __syncthreads();            // drains vmcnt -> LDS tiles visible
    bf16x8 af[4], bfr[4];
#pragma unroll
    for (int t = 0; t < 4; ++t) {
      af[t]  = *(const bf16x8*)(sA + (wm * 64 + t * 16 + r) * 32 + ko);
      bfr[t] = *(const bf16x8*)(sB + (wn * 64 + t * 16 + r) * 32 + ko);
    }
#pragma unroll
    for (int tm = 0; tm < 4; ++tm)
#pragma unroll
      for (int tn = 0; tn < 4; ++tn)
        acc.a[tm][tn] = __builtin_amdgcn_mfma_f32_16x16x32_bf16(
            af[tm], bfr[tn], acc.a[tm][tn], 0, 0, 0);
    __syncthreads();
  }
}

// Variant for k_attn: A-tile staged through registers applying on-the-fly
// softmax finalization p = (k<=q) ? exp(s - m) * inv : 0 (stats precomputed
// by k_sm_stats). Produces the IDENTICAL linear [128][32] LDS layout as
// stage_async (row r at byte r*64). B path unchanged (global_load_lds).
__device__ __forceinline__ void stage_P_exp(const bf16* __restrict__ g, int ldg,
                                            bf16* __restrict__ s, int k0g,
                                            int q0, int q1,
                                            float m0, float i0,
                                            float m1, float i1) {
  int lane = threadIdx.x & 63;
  int wave = threadIdx.x >> 6;
  bf16* lds = s + wave * 1024;           // 2048 B per wave chunk
  int r0 = wave * 32 + (lane >> 2);
  int col = (lane & 3) << 3;
  const bf16* g0 = g + (size_t)r0 * ldg + col;
  const bf16* g1 = g0 + (size_t)16 * ldg;
  bf16x8 v0 = *(const bf16x8*)g0;
  bf16x8 v1 = *(const bf16x8*)g1;
  int kb = k0g + col;
  bf16 t0[8], t1[8];
#pragma unroll
  for (int j = 0; j < 8; ++j) {
    float p0 = (kb + j <= q0) ? __expf(bs2f(v0[j]) - m0) * i0 : 0.0f;
    float p1 = (kb + j <= q1) ? __expf(bs2f(v1[j]) - m1) * i1 : 0.0f;
    t0[j] = f2b(p0);
    t1[j] = f2b(p1);
  }
  *(bf16x8*)(lds + lane * 8) = *(bf16x8*)t0;         // bytes: lane*16
  *(bf16x8*)(lds + 512 + lane * 8) = *(bf16x8*)t1;   // +1024 B (rows +16)
}

__device__ __forceinline__ void gemm_core_pexp(
    const bf16* __restrict__ A, const bf16* __restrict__ B, int K,
    int lda, int ldb, Acc& acc, bf16* sA, bf16* sB,
    const float2* __restrict__ st, int q0g) {
  int lane = threadIdx.x & 63;
  int wave = threadIdx.x >> 6;
  int wm = wave & 1, wn = wave >> 1;
  int r = lane & 15;
  int ko = (lane >> 4) << 3;
  int r0 = wave * 32 + (lane >> 2);   // this thread's two A-rows (local)
  float2 s0 = st[r0];
  float2 s1 = st[r0 + 16];
  int q0 = q0g + r0, q1 = q0 + 16;

  for (int k0 = 0; k0 < K; k0 += 32) {
    stage_P_exp(A + k0, lda, sA, k0, q0, q1, s0.x, s0.y, s1.x, s1.y);
    stage_async(B + k0, ldb, sB);
    __syncthreads();            // drains vmcnt+lgkm -> LDS tiles visible
    bf16x8 af[4], bfr[4];
#pragma unroll
    for (int t = 0; t < 4; ++t) {
      af[t]  = *(const bf16x8*)(sA + (wm * 64 + t * 16 + r) * 32 + ko);
      bfr[t] = *(const bf16x8*)(sB + (wn * 64 + t * 16 + r) * 32 + ko);
    }
#pragma unroll
    for (int tm = 0; tm < 4; ++tm)
#pragma unroll
      for (int tn = 0; tn < 4; ++tn)
        acc.a[tm][tn] = __builtin_amdgcn_mfma_f32_16x16x32_bf16(
            af[tm], bfr[tn], acc.a[tm][tn], 0, 0, 0);
    __syncthreads();
  }
}

// Epilogue: C/D layout col = lane&15, row = (lane>>4)*4 + reg (m89-verified)
template <typename TO, bool BIAS, bool GELU>
__device__ __forceinline__ void epilogue(const Acc& acc, TO* __restrict__ C,
                                         int ldc, const float* __restrict__ bias,
                                         float scale) {
  int lane = threadIdx.x & 63;
  int wave = threadIdx.x >> 6;
  int wm = wave & 1, wn = wave >> 1;
  int rbase = wm * 64 + ((lane >> 4) << 2);
  int cbase = wn * 64 + (lane & 15);
#pragma unroll
  for (int tm = 0; tm < 4; ++tm) {
#pragma unroll
    for (int tn = 0; tn < 4; ++tn) {
      int nn = cbase + tn * 16;
      float bv = BIAS ? bias[nn] : 0.0f;
#pragma unroll
      for (int rr = 0; rr < 4; ++rr) {
        int mm = rbase + tm * 16 + rr;
        float c = acc.a[tm][tn][rr] * scale + bv;
        if (GELU) c = gelu_f(c);
        if constexpr (__hip_internal::is_same<TO, bf16>::value)
          C[(size_t)mm * ldc + nn] = f2b(c);
        else
          C[(size_t)mm * ldc + nn] = c;
      }
    }
  }
}

// ===========================================================================
// NEW ENGINE: 256x256 tile, BK=64, 8 waves (2M x 4N), 512 threads, 128KB LDS.
// R1 schedule (measured best: 772 TF on k_ffn): 4 phases per K-tile, one
// half-tile staged per phase, counted vmcnt(4) twice per K-tile (issue-to-
// wait distance 3-4 phases, never 0 in loop). R2 deeper prefetch (12 in
// flight) and R3 read-hoist both measured null-to-negative — keep R1.
// LDS map per buffer (64KB): A kh0 [0,16K) | A kh1 [16K,32K) |
//                            B kh0 [32K,48K) | B kh1 [48K,64K)
// each 16KB region = 256 rows x 64B (32 bf16), row r slot s holds global
// k-slot s ^ ((r>>1)&3).
//   Swizzle: 64B rows -> bank(row start) = (16r)%32, period-2 in r. Key on
//   (r>>1)&3 -> quarter-wave start banks each hit 2x -> 2-way = free (m136).
//   Verified: 6.3M conflicts -> 0 (round 2).
// ===========================================================================
struct Acc256 { f32x4 a[8][4]; };

// Stage one 16KB half-tile (256 rows x 32 cols bf16) = 2 gload_lds/thread.
__device__ __forceinline__ void stage_half(const bf16* __restrict__ g, int ld,
                                           int kOff, char* lds) {
  int t = threadIdx.x;          // 0..511
  int w = t >> 6;
#pragma unroll
  for (int j = 0; j < 2; ++j) {
    int c = j * 512 + t;        // chunk 0..1023 (16B each)
    int r = c >> 2;             // row 0..255
    int s = (c & 3) ^ ((r >> 1) & 3);  // inverse-swizzled source slot
    const bf16* src = g + (size_t)r * ld + kOff + s * 8;
    char* dst = lds + (j * 512 + w * 64) * 16;  // wave-uniform; HW adds lane*16
    __builtin_amdgcn_global_load_lds((GLOBAL_AS const unsigned*)src,
                                     (LDS_AS unsigned*)dst, 16, 0, 0);
  }
}

__device__ __forceinline__ void gemm256_core(
    const bf16* __restrict__ A, const bf16* __restrict__ B, int K,
    int lda, int ldb, Acc256& acc, char* arena) {
  const int lane = threadIdx.x & 63;
  const int wave = threadIdx.x >> 6;
  const int wm = wave >> 2, wn = wave & 3;   // 2M x 4N wave grid
  const int r15 = lane & 15, q = lane >> 4;

  const int NT = K >> 6;

  // Per-lane base read offsets. Swizzle term constant across the i*1024
  // fragment offsets: row stride 16 -> (row>>1) changes by 8 == 0 mod 4.
  const int arow = wm * 128 + r15;
  const int brow = wn * 64 + r15;
  const int aoff = arow * 64 + ((q ^ ((arow >> 1) & 3)) << 4);
  const int boff = brow * 64 + ((q ^ ((brow >> 1) & 3)) << 4) + 32768;

  // Prologue: tile 0 fully issued; wait only for kh0 (kh1 stays in flight).
  stage_half(A, lda, 0, arena);
  stage_half(B, ldb, 0, arena + 32768);
  stage_half(A, lda, 32, arena + 16384);
  stage_half(B, ldb, 32, arena + 49152);
  asm volatile("s_waitcnt vmcnt(4)" ::: "memory");
  __builtin_amdgcn_s_barrier();

#pragma unroll 2
  for (int t = 0; t < NT; ++t) {
    char* cb = arena + ((t & 1) << 16);
    char* nb = arena + (((t + 1) & 1) << 16);
    int nk = ((t + 1 < NT) ? (t + 1) : t) << 6;  // clamp: last restage unread

    bf16x8 af[4], bfr[4];
    // ---- phase 0: ks=0, mt 0..3 (reads kh0 of tile t; stages A-kh0 t+1) ----
#pragma unroll
    for (int i = 0; i < 4; ++i) {
      bfr[i] = *(const bf16x8*)(cb + boff + i * 1024);
      af[i]  = *(const bf16x8*)(cb + aoff + i * 1024);
    }
    stage_half(A, lda, nk, nb);
    __builtin_amdgcn_s_barrier();
    __builtin_amdgcn_s_setprio(1);
#pragma unroll
    for (int m = 0; m < 4; ++m)
#pragma unroll
      for (int n = 0; n < 4; ++n)
        acc.a[m][n] = __builtin_amdgcn_mfma_f32_16x16x32_bf16(
            af[m], bfr[n], acc.a[m][n], 0, 0, 0);
    __builtin_amdgcn_s_setprio(0);
    __builtin_amdgcn_s_barrier();

    // ---- phase 1: ks=0, mt 4..7 (stages B-kh0 t+1; release kh1 of t) ----
#pragma unroll
    for (int i = 0; i < 4; ++i)
      af[i] = *(const bf16x8*)(cb + aoff + (i + 4) * 1024);
    stage_half(B, ldb, nk, nb + 32768);
    __builtin_amdgcn_s_barrier();
    __builtin_amdgcn_s_setprio(1);
#pragma unroll
    for (int m = 0; m < 4; ++m)
#pragma unroll
      for (int n = 0; n < 4; ++n)
        acc.a[m + 4][n] = __builtin_amdgcn_mfma_f32_16x16x32_bf16(
            af[m], bfr[n], acc.a[m + 4][n], 0, 0, 0);
    __builtin_amdgcn_s_setprio(0);
    // oldest 4 outstanding = kh1(t) A,B -> complete, then barrier releases it
    asm volatile("s_waitcnt vmcnt(4)" ::: "memory");
    __builtin_amdgcn_s_barrier();

    // ---- phase 2: ks=1, mt 0..3 (reads kh1 of t; stages A-kh1 t+1) ----
#pragma unroll
    for (int i = 0; i < 4; ++i) {
      bfr[i] = *(const bf16x8*)(cb + 16384 + boff + i * 1024);
      af[i]  = *(const bf16x8*)(cb + 16384 + aoff + i * 1024);
    }
    stage_half(A, lda, nk + 32, nb + 16384);
    __builtin_amdgcn_s_barrier();
    __builtin_amdgcn_s_setprio(1);
#pragma unroll
    for (int m = 0; m < 4; ++m)
#pragma unroll
      for (int n = 0; n < 4; ++n)
        acc.a[m][n] = __builtin_amdgcn_mfma_f32_16x16x32_bf16(
            af[m], bfr[n], acc.a[m][n], 0, 0, 0);
    __builtin_amdgcn_s_setprio(0);
    __builtin_amdgcn_s_barrier();

    // ---- phase 3: ks=1, mt 4..7 (stages B-kh1 t+1; release kh0 of t+1) ----
#pragma unroll
    for (int i = 0; i < 4; ++i)
      af[i] = *(const bf16x8*)(cb + 16384 + aoff + (i + 4) * 1024);
    stage_half(B, ldb, nk + 32, nb + 49152);
    __builtin_amdgcn_s_barrier();
    __builtin_amdgcn_s_setprio(1);
#pragma unroll
    for (int m = 0; m < 4; ++m)
#pragma unroll
      for (int n = 0; n < 4; ++n)
        acc.a[m + 4][n] = __builtin_amdgcn_mfma_f32_16x16x32_bf16(
            af[m], bfr[n], acc.a[m + 4][n], 0, 0, 0);
    __builtin_amdgcn_s_setprio(0);
    // oldest 4 outstanding = kh0(t+1) A,B -> complete; barrier -> next tile
    asm volatile("s_waitcnt vmcnt(4)" ::: "memory");
    __builtin_amdgcn_s_barrier();
  }
  asm volatile("s_waitcnt vmcnt(0)" ::: "memory");  // drain bogus last restage
}

// Epilogue: per wave 128x64; frag (mt,nt): row = wm*128+mt*16+(lane>>4)*4+rr,
// col = wn*64+nt*16+(lane&15). Same m89-verified C/D layout as old engine.
template <typename TO, bool BIAS, bool GELU>
__device__ __forceinline__ void epilogue256(const Acc256& acc, TO* __restrict__ C,
                                            int ldc, const float* __restrict__ bias,
                                            float scale) {
  int lane = threadIdx.x & 63;
  int wave = threadIdx.x >> 6;
  int wm = wave >> 2, wn = wave & 3;
  int rbase = wm * 128 + ((lane >> 4) << 2);
  int cbase = wn * 64 + (lane & 15);
#pragma unroll
  for (int mt = 0; mt < 8; ++mt) {
#pragma unroll
    for (int nt = 0; nt < 4; ++nt) {
      int nn = cbase + nt * 16;
      float bv = BIAS ? bias[nn] : 0.0f;
#pragma unroll
      for (int rr = 0; rr < 4; ++rr) {
        int mm = rbase + mt * 16 + rr;
        float c = acc.a[mt][nt][rr] * scale + bv;
        if (GELU) c = gelu_f(c);
        if constexpr (__hip_internal::is_same<TO, bf16>::value)
          C[(size_t)mm * ldc + nn] = f2b(c);
        else
          C[(size_t)mm * ldc + nn] = c;
      }
    }
  }
}

// ---------------------------------------------------------------------------
// Kernel 1a: Q,K projections (256^2 engine). grid (32,4,2): z=0->Q, z=1->K.
// ---------------------------------------------------------------------------
__global__ __launch_bounds__(512, 2) void k_qkv256(
    const bf16* __restrict__ X, const bf16* __restrict__ Wq,
    const bf16* __restrict__ Wk, const float* __restrict__ bq,
    const float* __restrict__ bk, bf16* __restrict__ Q,
    bf16* __restrict__ Ko) {
  __shared__ alignas(16) char arena[131072];
  const int K = 1024, N = 1024;
  int z = blockIdx.z;
  const bf16* W = z ? Wk : Wq;
  const float* bias = z ? bk : bq;
  const bf16* A = X + (size_t)blockIdx.x * 256 * K;
  const bf16* B = W + (size_t)blockIdx.y * 256 * K;
  Acc256 acc = {};
  gemm256_core(A, B, K, K, K, acc, arena);
  bf16* C = (z ? Ko : Q) + (size_t)blockIdx.x * 256 * N + blockIdx.y * 256;
  epilogue256<bf16, true, false>(acc, C, N, bias + blockIdx.y * 256, 1.0f);
}

// ---------------------------------------------------------------------------
// Kernel 1b: V projection, stored transposed Vt[b][d][s] (old engine +
// verified LDS-transpose epilogue). grid (64,8).
// ---------------------------------------------------------------------------
__global__ __launch_bounds__(256) void k_v(
    const bf16* __restrict__ X, const bf16* __restrict__ Wv,
    const float* __restrict__ bv, bf16* __restrict__ Vt) {
  __shared__ alignas(16) char arena[17408];  // 16KB GEMM | 17.4KB transpose
  bf16* sA = (bf16*)arena;
  bf16* sB = (bf16*)(arena + 8192);
  const int K = 1024;
  const bf16* A = X + (size_t)blockIdx.x * 128 * K;
  const bf16* B = Wv + (size_t)blockIdx.y * 128 * K;
  Acc acc = {};
  gemm_core(A, B, K, K, K, acc, sA, sB);

  bf16* sT = (bf16*)arena;  // 64 x 136 bf16 = 17408 B (GEMM arena dead)
  int tid = threadIdx.x;
  int lane = tid & 63;
  int wave = tid >> 6;
  int wm = wave & 1, wn = wave >> 1;
  int b  = blockIdx.x >> 4;               // batch
  int s0 = (blockIdx.x & 15) * 128;       // seq base within batch
#pragma unroll
  for (int p = 0; p < 2; ++p) {           // 64 d-rows per pass
    __syncthreads();
    if (wn == p) {
      int rloc_s = wm * 64 + ((lane >> 4) << 2);   // local token
#pragma unroll
      for (int tn = 0; tn < 4; ++tn) {
        int nl = (lane & 15) + tn * 16;            // local d within pass
        float bvv = bv[blockIdx.y * 128 + p * 64 + nl];
#pragma unroll
        for (int tm = 0; tm < 4; ++tm)
#pragma unroll
          for (int rr = 0; rr < 4; ++rr)
            sT[nl * 136 + rloc_s + tm * 16 + rr] =
                f2b(acc.a[tm][tn][rr] + bvv);
      }
    }
    __syncthreads();
    int c = tid & 15, r0 = tid >> 4;      // 16 col-chunks x 16 rows
#pragma unroll
    for (int j = 0; j < 4; ++j) {
      int rl = r0 + j * 16;               // local d row (0..63)
      int n = blockIdx.y * 128 + p * 64 + rl;
      *(bf16x8*)(Vt + ((size_t)b * 1024 + n) * 2048 + s0 + c * 8) =
          *(const bf16x8*)(sT + rl * 136 + c * 8);
    }
  }
}

// ---------------------------------------------------------------------------
// Kernel 2: scores = Q K^T / 32 per batch (256^2 engine — measured better
// than 128^2 despite 144-block grid: R2 454 vs R3 471). grid (8,8,4).
// bx descending; upper-triangle 256-tiles skipped.
// ---------------------------------------------------------------------------
__global__ __launch_bounds__(512, 2) void k_scores256(
    const bf16* __restrict__ Q, const bf16* __restrict__ Kk,
    bf16* __restrict__ P) {
  int bx = 7 - (int)blockIdx.x;
  if ((int)blockIdx.y > bx) return;  // fully masked tile (never read later)
  __shared__ alignas(16) char arena[131072];
  const int K = 1024, S = 2048;
  int z = blockIdx.z;
  const bf16* A = Q + (size_t)z * S * K + (size_t)bx * 256 * K;
  const bf16* B = Kk + (size_t)z * S * K + (size_t)blockIdx.y * 256 * K;
  Acc256 acc = {};
  gemm256_core(A, B, K, K, K, acc, arena);
  bf16* C = P + (size_t)z * S * S + (size_t)bx * 256 * S + blockIdx.y * 256;
  epilogue256<bf16, false, false>(acc, C, S, nullptr, 0.03125f);
}

// ---------------------------------------------------------------------------
// Kernel 3: softmax STATS only (max, 1/sum per row) — the normalization is
// applied on the fly inside k_attn's A-staging. Saves the 32MB P write-back
// and one 32MB re-read. grid (2048,4).
// ---------------------------------------------------------------------------
__global__ __launch_bounds__(256) void k_sm_stats(const bf16* __restrict__ P,
                                                  float2* __restrict__ st) {
  const int S = 2048;
  int q = blockIdx.x, z = blockIdx.y;
  const bf16* row = P + ((size_t)z * S + q) * S;
  __shared__ float red[4];
  int tid = threadIdx.x;
  int kcap = ((q >> 7) + 1) << 7;
  int nch = kcap >> 3;             // 8-elem chunks (kcap % 8 == 0)

  float mx = -1e30f;
  for (int c = tid; c < nch; c += 256) {
    int k = c << 3;
    bf16x8 v = *(const bf16x8*)(row + k);
#pragma unroll
    for (int j = 0; j < 8; ++j)
      if (k + j <= q) mx = fmaxf(mx, bs2f(v[j]));
  }
#pragma unroll
  for (int o = 32; o > 0; o >>= 1) mx = fmaxf(mx, __shfl_xor(mx, o));
  if ((tid & 63) == 0) red[tid >> 6] = mx;
  __syncthreads();
  mx = fmaxf(fmaxf(red[0], red[1]), fmaxf(red[2], red[3]));
  __syncthreads();

  float sum = 0.0f;
  for (int c = tid; c < nch; c += 256) {
    int k = c << 3;
    bf16x8 v = *(const bf16x8*)(row + k);
#pragma unroll
    for (int j = 0; j < 8; ++j)
      if (k + j <= q) sum += __expf(bs2f(v[j]) - mx);
  }
#pragma unroll
  for (int o = 32; o > 0; o >>= 1) sum += __shfl_xor(sum, o);
  if ((tid & 63) == 0) red[tid >> 6] = sum;
  __syncthreads();
  if (tid == 0) {
    sum = red[0] + red[1] + red[2] + red[3];
    st[(size_t)z * S + q] = make_float2(mx, 1.0f / sum);
  }
}

// ---------------------------------------------------------------------------
// Kernel 4: attn = softmax(P) @ V fused (B = Vt, K-major). grid (16,8,4).
// A-tiles reg-staged with exp(s-m)*inv + per-element causal mask (replaces
// the old tail-zeroing). Triangular: K-loop stops at (bx+1)*128.
// ---------------------------------------------------------------------------
__global__ __launch_bounds__(256) void k_attn(const bf16* __restrict__ P,
                                              const bf16* __restrict__ Vt,
                                              const float2* __restrict__ stats,
                                              bf16* __restrict__ O) {
  __shared__ alignas(16) char arena[16384];
  bf16* sA = (bf16*)arena;
  bf16* sB = (bf16*)(arena + 8192);
  const int S = 2048, D = 1024;
  int bx = 15 - (int)blockIdx.x;
  int z = blockIdx.z;
  int Keff = (bx + 1) * 128;
  const bf16* A = P  + (size_t)z * S * S + (size_t)bx * 128 * S;
  const bf16* B = Vt + (size_t)z * D * S + (size_t)blockIdx.y * 128 * S;
  const float2* st = stats + (size_t)z * S + bx * 128;  // local-row indexed
  Acc acc = {};
  gemm_core_pexp(A, B, Keff, S, S, acc, sA, sB, st, bx * 128);
  bf16* C = O + (size_t)z * S * D + (size_t)bx * 128 * D + blockIdx.y * 128;
  epilogue<bf16, false, false>(acc, C, D, nullptr, 1.0f);
}

// ---------------------------------------------------------------------------
// Kernel 5: out = attn @ Wo^T + bo (Wob bf16). grid (64,8). (old engine:
// 256^2 would give 128 blocks -> half-GPU)
// ---------------------------------------------------------------------------
__global__ __launch_bounds__(256) void k_out(const bf16* __restrict__ A0,
                                             const bf16* __restrict__ W,
                                             const float* __restrict__ bias,
                                             bf16* __restrict__ C0) {
  __shared__ alignas(16) char arena[16384];
  bf16* sA = (bf16*)arena;
  bf16* sB = (bf16*)(arena + 8192);
  const int K = 1024, N = 1024;
  const bf16* A = A0 + (size_t)blockIdx.x * 128 * K;
  const bf16* B = W + (size_t)blockIdx.y * 128 * K;
  Acc acc = {};
  gemm_core(A, B, K, K, K, acc, sA, sB);
  bf16* C = C0 + (size_t)blockIdx.x * 128 * N + blockIdx.y * 128;
  epilogue<bf16, true, false>(acc, C, N, bias + blockIdx.y * 128, 1.0f);
}

// ---------------------------------------------------------------------------
// Kernel 6: ff = GELU(out @ Wf^T + bf) -> f32 d_out (256^2 engine).
// grid (32,16) = 512 blocks = 2 perfectly balanced rounds on 256 CUs.
// ---------------------------------------------------------------------------
__global__ __launch_bounds__(512, 2) void k_ffn256(
    const bf16* __restrict__ A0, const bf16* __restrict__ W,
    const float* __restrict__ bias, float* __restrict__ C0) {
  __shared__ alignas(16) char arena[131072];
  const int K = 1024, N = 4096;
  const bf16* A = A0 + (size_t)blockIdx.x * 256 * K;
  const bf16* B = W + (size_t)blockIdx.y * 256 * K;
  Acc256 acc = {};
  gemm256_core(A, B, K, K, K, acc, arena);
  float* C = C0 + (size_t)blockIdx.x * 256 * N + blockIdx.y * 256;
  epilogue256<float, true, true>(acc, C, N, bias + blockIdx.y * 256, 1.0f);
}

// ---------------------------------------------------------------------------
// Workspace (80 MB), liveness-based reuse across the 5 x 16MB regions:
//   A [0,16):   xb (conv -> qkv)        | then P[0:16M)   (scores..attn)
//   B [16,32):  Wqb,Wkb,Wvb (6MB)       | then P[16M:32M)
//   C [32,48):  Q  (qkv -> scores)      | then attn (attn -> out)
//   D [48,64):  K  (qkv -> scores)      | then Wob(2MB)+Wfb(8MB)+stats@62M
//   E [64,80):  Vt (qkv -> attn)        | then out (out -> ffn)
// ---------------------------------------------------------------------------
extern "C" void kernel_launch(void* const* d_in, const int* in_sizes, int n_in,
                              void* d_out, int out_size, void* d_ws,
                              size_t ws_size, hipStream_t stream) {
  const float* x   = (const float*)d_in[0];
  const float* Wq  = (const float*)d_in[1];
  const float* bq  = (const float*)d_in[2];
  const float* Wk  = (const float*)d_in[3];
  const float* bk  = (const float*)d_in[4];
  const float* Wv  = (const float*)d_in[5];
  const float* bv  = (const float*)d_in[6];
  const float* Wo  = (const float*)d_in[7];
  const float* bo  = (const float*)d_in[8];
  const float* Wf  = (const float*)d_in[9];
  const float* bfb = (const float*)d_in[10];

  char* ws = (char*)d_ws;
  const size_t MB = 1 << 20;
  bf16* xb   = (bf16*)(ws);                  // A
  bf16* Wqb  = (bf16*)(ws + 16 * MB);        // B
  bf16* Wkb  = (bf16*)(ws + 18 * MB);
  bf16* Wvb  = (bf16*)(ws + 20 * MB);
  bf16* P    = (bf16*)(ws);                  // A+B after qkv
  bf16* Q    = (bf16*)(ws + 32 * MB);        // C
  bf16* Kb   = (bf16*)(ws + 48 * MB);        // D
  bf16* Wob  = (bf16*)(ws + 48 * MB);        // D after scores
  bf16* Wfb  = (bf16*)(ws + 50 * MB);
  float2* smst = (float2*)(ws + 62 * MB);    // D tail: 64KB softmax stats
  bf16* Vt   = (bf16*)(ws + 64 * MB);        // E
  bf16* attn = Q;                            // C after scores
  bf16* out  = Vt;                           // E after attn
  float* y   = (float*)d_out;

  k_conv4<<<11264, 256, 0, stream>>>(x, Wq, Wk, Wv, xb, Wqb, Wkb, Wvb);
  k_qkv256<<<dim3(32, 4, 2), 512, 0, stream>>>(xb, Wqb, Wkb, bq, bk, Q, Kb);
  k_v<<<dim3(64, 8), 256, 0, stream>>>(xb, Wvb, bv, Vt);
  k_scores256<<<dim3(8, 8, 4), 512, 0, stream>>>(Q, Kb, P);
  k_conv2<<<5120, 256, 0, stream>>>(Wo, Wf, Wob, Wfb);
  k_sm_stats<<<dim3(2048, 4), 256, 0, stream>>>(P, smst);
  k_attn<<<dim3(16, 8, 4), 256, 0, stream>>>(P, Vt, smst, attn);
  k_out<<<dim3(64, 8), 256, 0, stream>>>(attn, Wob, bo, out);
  k_ffn256<<<dim3(32, 16), 512, 0, stream>>>(out, Wfb, bfb, y);
}

// Round 6
// 436.307 us; speedup vs baseline: 1.1031x; 1.1031x over previous
//
#include <hip/hip_runtime.h>
#include <hip/hip_bf16.h>
#include <math.h>

using bf16 = __hip_bfloat16;
typedef __attribute__((ext_vector_type(8))) short bf16x8;  // 8 bf16 = 4 VGPRs
typedef __attribute__((ext_vector_type(4))) short bf16x4;  // 4 bf16 = 2 VGPRs
typedef __attribute__((ext_vector_type(4))) float f32x4;

#define GLOBAL_AS __attribute__((address_space(1)))
#define LDS_AS __attribute__((address_space(3)))

__device__ __forceinline__ float b2f(bf16 v) { return __bfloat162float(v); }
__device__ __forceinline__ bf16 f2b(float v) { return __float2bfloat16(v); }
__device__ __forceinline__ float bs2f(short s) {
  union { unsigned u; float f; } x;
  x.u = ((unsigned)(unsigned short)s) << 16;
  return x.f;
}

// Fast GELU (tanh form via hw exp): |err| vs erf-GELU <= ~2e-4 absolute.
__device__ __forceinline__ float gelu_f(float x) {
  float u = x * (0.7978845608f + 0.0356774081f * x * x);
  float t = 1.0f - 2.0f / (1.0f + __expf(2.0f * u));
  return 0.5f * x * (1.0f + t);
}

// ---------------------------------------------------------------------------
// Fused f32->bf16 conversion for x, Wq, Wk, Wv. 4 elem/thread.
// blocks: x 8192 | Wq 1024 | Wk 1024 | Wv 1024  (grid 11264)
// ---------------------------------------------------------------------------
__global__ __launch_bounds__(256) void k_conv4(
    const float* __restrict__ x, const float* __restrict__ Wq,
    const float* __restrict__ Wk, const float* __restrict__ Wv,
    bf16* __restrict__ xb, bf16* __restrict__ Wqb,
    bf16* __restrict__ Wkb, bf16* __restrict__ Wvb) {
  int bid = blockIdx.x;
  const float* src;
  bf16* dst;
  int local;
  if (bid < 8192) { src = x; dst = xb; local = bid; }
  else {
    int b2 = bid - 8192;
    int w = b2 >> 10;
    local = b2 & 1023;
    src = (w == 0) ? Wq : (w == 1) ? Wk : Wv;
    dst = (w == 0) ? Wqb : (w == 1) ? Wkb : Wvb;
  }
  int i = local * 256 + threadIdx.x;
  float4 v = ((const float4*)src)[i];
  bf16 t[4] = {f2b(v.x), f2b(v.y), f2b(v.z), f2b(v.w)};
  *(bf16x4*)(dst + 4 * (size_t)i) = *(bf16x4*)t;
}

// Fused conversion for Wo (1024 blocks) + Wf (4096 blocks). grid 5120.
__global__ __launch_bounds__(256) void k_conv2(
    const float* __restrict__ Wo, const float* __restrict__ Wf,
    bf16* __restrict__ Wob, bf16* __restrict__ Wfb) {
  int bid = blockIdx.x;
  const float* src = (bid < 1024) ? Wo : Wf;
  bf16* dst = (bid < 1024) ? Wob : Wfb;
  int local = (bid < 1024) ? bid : bid - 1024;
  int i = local * 256 + threadIdx.x;
  float4 v = ((const float4*)src)[i];
  bf16 t[4] = {f2b(v.x), f2b(v.y), f2b(v.z), f2b(v.w)};
  *(bf16x4*)(dst + 4 * (size_t)i) = *(bf16x4*)t;
}

// ===========================================================================
// OLD ENGINE (m97 structure, 128x128 tile, 256 threads) — kept for k_v /
// k_attn / k_out where 256^2 tiles would under-fill the grid.
// R5: slot-XOR swizzle ported from the 256^2 engine (both-sides, rule #21).
//   Unswizzled, lane (q,r) read byte row*64 + q*16 -> bank (16(r&1)+4q)%32:
//   8 bank-quads for 64 lanes = 8-way conflict (round-0 counter: 8.39M on
//   the old k_ffn). With slot ^= (row>>1)&3 (verified 6.3M->0 on the 256^2
//   engine): start banks {0,4,..,28} each 2 lanes -> 2-way = free (m136).
//   Key invariant across t (row stride 16 -> (row>>1) += 8 == 0 mod 4) and
//   across the g0/g1 halves (row+16).
// ===========================================================================
__device__ __forceinline__ void stage_async(const bf16* __restrict__ g,
                                            int ldg, bf16* __restrict__ s) {
  int lane = threadIdx.x & 63;
  int wave = threadIdx.x >> 6;
  bf16* lds = s + wave * 1024;  // 2048 B per wave chunk (dest linear: lane*16)
  int row = wave * 32 + (lane >> 2);
  int slot = (lane & 3) ^ ((row >> 1) & 3);   // inverse-swizzled source slot
  const bf16* g0 = g + (size_t)row * ldg + (slot << 3);
  const bf16* g1 = g0 + (size_t)16 * ldg;     // row+16: key unchanged
  __builtin_amdgcn_global_load_lds((GLOBAL_AS const unsigned*)g0,
                                   (LDS_AS unsigned*)lds, 16, 0, 0);
  __builtin_amdgcn_global_load_lds((GLOBAL_AS const unsigned*)g1,
                                   (LDS_AS unsigned*)(lds + 512), 16, 0, 0);
}

struct Acc { f32x4 a[4][4]; };

__device__ __forceinline__ void gemm_core(const bf16* __restrict__ A,
                                          const bf16* __restrict__ B,
                                          int K, int lda, int ldb, Acc& acc,
                                          bf16* sA, bf16* sB) {
  int lane = threadIdx.x & 63;
  int wave = threadIdx.x >> 6;
  int wm = wave & 1, wn = wave >> 1;
  int r = lane & 15;            // operand row: m (or n) = lane&15
  int q = lane >> 4;
  // swizzled k offset: LDS slot q^key holds global slot q (key=(r>>1)&3,
  // constant across t and wm/wn since their row terms are ==0 mod 8)
  int ko = (q ^ ((r >> 1) & 3)) << 3;

  for (int k0 = 0; k0 < K; k0 += 32) {
    stage_async(A + k0, lda, sA);
    stage_async(B + k0, ldb, sB);
    __syncthreads();            // drains vmcnt -> LDS tiles visible
    bf16x8 af[4], bfr[4];
#pragma unroll
    for (int t = 0; t < 4; ++t) {
      af[t]  = *(const bf16x8*)(sA + (wm * 64 + t * 16 + r) * 32 + ko);
      bfr[t] = *(const bf16x8*)(sB + (wn * 64 + t * 16 + r) * 32 + ko);
    }
#pragma unroll
    for (int tm = 0; tm < 4; ++tm)
#pragma unroll
      for (int tn = 0; tn < 4; ++tn)
        acc.a[tm][tn] = __builtin_amdgcn_mfma_f32_16x16x32_bf16(
            af[tm], bfr[tn], acc.a[tm][tn], 0, 0, 0);
    __syncthreads();
  }
}

// Epilogue: C/D layout col = lane&15, row = (lane>>4)*4 + reg (m89-verified)
template <typename TO, bool BIAS, bool GELU>
__device__ __forceinline__ void epilogue(const Acc& acc, TO* __restrict__ C,
                                         int ldc, const float* __restrict__ bias,
                                         float scale) {
  int lane = threadIdx.x & 63;
  int wave = threadIdx.x >> 6;
  int wm = wave & 1, wn = wave >> 1;
  int rbase = wm * 64 + ((lane >> 4) << 2);
  int cbase = wn * 64 + (lane & 15);
#pragma unroll
  for (int tm = 0; tm < 4; ++tm) {
#pragma unroll
    for (int tn = 0; tn < 4; ++tn) {
      int nn = cbase + tn * 16;
      float bv = BIAS ? bias[nn] : 0.0f;
#pragma unroll
      for (int rr = 0; rr < 4; ++rr) {
        int mm = rbase + tm * 16 + rr;
        float c = acc.a[tm][tn][rr] * scale + bv;
        if (GELU) c = gelu_f(c);
        if constexpr (__hip_internal::is_same<TO, bf16>::value)
          C[(size_t)mm * ldc + nn] = f2b(c);
        else
          C[(size_t)mm * ldc + nn] = c;
      }
    }
  }
}

// ===========================================================================
// NEW ENGINE: 256x256 tile, BK=64, 8 waves (2M x 4N), 512 threads, 128KB LDS.
// R1 schedule (measured best: 772 TF on k_ffn): 4 phases per K-tile, one
// half-tile staged per phase, counted vmcnt(4) twice per K-tile (issue-to-
// wait distance 3-4 phases, never 0 in loop). R2 deeper prefetch (12 in
// flight) and R3 read-hoist both measured null-to-negative; R4 softmax
// fusion into the A-path regressed (+27us) — keep R1 exactly.
// LDS map per buffer (64KB): A kh0 [0,16K) | A kh1 [16K,32K) |
//                            B kh0 [32K,48K) | B kh1 [48K,64K)
// each 16KB region = 256 rows x 64B (32 bf16), row r slot s holds global
// k-slot s ^ ((r>>1)&3).
//   Swizzle: 64B rows -> bank(row start) = (16r)%32, period-2 in r. Key on
//   (r>>1)&3 -> quarter-wave start banks each hit 2x -> 2-way = free (m136).
//   Verified: 6.3M conflicts -> 0 (round 2).
// ===========================================================================
struct Acc256 { f32x4 a[8][4]; };

// Stage one 16KB half-tile (256 rows x 32 cols bf16) = 2 gload_lds/thread.
__device__ __forceinline__ void stage_half(const bf16* __restrict__ g, int ld,
                                           int kOff, char* lds) {
  int t = threadIdx.x;          // 0..511
  int w = t >> 6;
#pragma unroll
  for (int j = 0; j < 2; ++j) {
    int c = j * 512 + t;        // chunk 0..1023 (16B each)
    int r = c >> 2;             // row 0..255
    int s = (c & 3) ^ ((r >> 1) & 3);  // inverse-swizzled source slot
    const bf16* src = g + (size_t)r * ld + kOff + s * 8;
    char* dst = lds + (j * 512 + w * 64) * 16;  // wave-uniform; HW adds lane*16
    __builtin_amdgcn_global_load_lds((GLOBAL_AS const unsigned*)src,
                                     (LDS_AS unsigned*)dst, 16, 0, 0);
  }
}

__device__ __forceinline__ void gemm256_core(
    const bf16* __restrict__ A, const bf16* __restrict__ B, int K,
    int lda, int ldb, Acc256& acc, char* arena) {
  const int lane = threadIdx.x & 63;
  const int wave = threadIdx.x >> 6;
  const int wm = wave >> 2, wn = wave & 3;   // 2M x 4N wave grid
  const int r15 = lane & 15, q = lane >> 4;

  const int NT = K >> 6;

  // Per-lane base read offsets. Swizzle term constant across the i*1024
  // fragment offsets: row stride 16 -> (row>>1) changes by 8 == 0 mod 4.
  const int arow = wm * 128 + r15;
  const int brow = wn * 64 + r15;
  const int aoff = arow * 64 + ((q ^ ((arow >> 1) & 3)) << 4);
  const int boff = brow * 64 + ((q ^ ((brow >> 1) & 3)) << 4) + 32768;

  // Prologue: tile 0 fully issued; wait only for kh0 (kh1 stays in flight).
  stage_half(A, lda, 0, arena);
  stage_half(B, ldb, 0, arena + 32768);
  stage_half(A, lda, 32, arena + 16384);
  stage_half(B, ldb, 32, arena + 49152);
  asm volatile("s_waitcnt vmcnt(4)" ::: "memory");
  __builtin_amdgcn_s_barrier();

#pragma unroll 2
  for (int t = 0; t < NT; ++t) {
    char* cb = arena + ((t & 1) << 16);
    char* nb = arena + (((t + 1) & 1) << 16);
    int nk = ((t + 1 < NT) ? (t + 1) : t) << 6;  // clamp: last restage unread

    bf16x8 af[4], bfr[4];
    // ---- phase 0: ks=0, mt 0..3 (reads kh0 of tile t; stages A-kh0 t+1) ----
#pragma unroll
    for (int i = 0; i < 4; ++i) {
      bfr[i] = *(const bf16x8*)(cb + boff + i * 1024);
      af[i]  = *(const bf16x8*)(cb + aoff + i * 1024);
    }
    stage_half(A, lda, nk, nb);
    __builtin_amdgcn_s_barrier();
    __builtin_amdgcn_s_setprio(1);
#pragma unroll
    for (int m = 0; m < 4; ++m)
#pragma unroll
      for (int n = 0; n < 4; ++n)
        acc.a[m][n] = __builtin_amdgcn_mfma_f32_16x16x32_bf16(
            af[m], bfr[n], acc.a[m][n], 0, 0, 0);
    __builtin_amdgcn_s_setprio(0);
    __builtin_amdgcn_s_barrier();

    // ---- phase 1: ks=0, mt 4..7 (stages B-kh0 t+1; release kh1 of t) ----
#pragma unroll
    for (int i = 0; i < 4; ++i)
      af[i] = *(const bf16x8*)(cb + aoff + (i + 4) * 1024);
    stage_half(B, ldb, nk, nb + 32768);
    __builtin_amdgcn_s_barrier();
    __builtin_amdgcn_s_setprio(1);
#pragma unroll
    for (int m = 0; m < 4; ++m)
#pragma unroll
      for (int n = 0; n < 4; ++n)
        acc.a[m + 4][n] = __builtin_amdgcn_mfma_f32_16x16x32_bf16(
            af[m], bfr[n], acc.a[m + 4][n], 0, 0, 0);
    __builtin_amdgcn_s_setprio(0);
    // oldest 4 outstanding = kh1(t) A,B -> complete, then barrier releases it
    asm volatile("s_waitcnt vmcnt(4)" ::: "memory");
    __builtin_amdgcn_s_barrier();

    // ---- phase 2: ks=1, mt 0..3 (reads kh1 of t; stages A-kh1 t+1) ----
#pragma unroll
    for (int i = 0; i < 4; ++i) {
      bfr[i] = *(const bf16x8*)(cb + 16384 + boff + i * 1024);
      af[i]  = *(const bf16x8*)(cb + 16384 + aoff + i * 1024);
    }
    stage_half(A, lda, nk + 32, nb + 16384);
    __builtin_amdgcn_s_barrier();
    __builtin_amdgcn_s_setprio(1);
#pragma unroll
    for (int m = 0; m < 4; ++m)
#pragma unroll
      for (int n = 0; n < 4; ++n)
        acc.a[m][n] = __builtin_amdgcn_mfma_f32_16x16x32_bf16(
            af[m], bfr[n], acc.a[m][n], 0, 0, 0);
    __builtin_amdgcn_s_setprio(0);
    __builtin_amdgcn_s_barrier();

    // ---- phase 3: ks=1, mt 4..7 (stages B-kh1 t+1; release kh0 of t+1) ----
#pragma unroll
    for (int i = 0; i < 4; ++i)
      af[i] = *(const bf16x8*)(cb + 16384 + aoff + (i + 4) * 1024);
    stage_half(B, ldb, nk + 32, nb + 49152);
    __builtin_amdgcn_s_barrier();
    __builtin_amdgcn_s_setprio(1);
#pragma unroll
    for (int m = 0; m < 4; ++m)
#pragma unroll
      for (int n = 0; n < 4; ++n)
        acc.a[m + 4][n] = __builtin_amdgcn_mfma_f32_16x16x32_bf16(
            af[m], bfr[n], acc.a[m + 4][n], 0, 0, 0);
    __builtin_amdgcn_s_setprio(0);
    // oldest 4 outstanding = kh0(t+1) A,B -> complete; barrier -> next tile
    asm volatile("s_waitcnt vmcnt(4)" ::: "memory");
    __builtin_amdgcn_s_barrier();
  }
  asm volatile("s_waitcnt vmcnt(0)" ::: "memory");  // drain bogus last restage
}

// Epilogue: per wave 128x64; frag (mt,nt): row = wm*128+mt*16+(lane>>4)*4+rr,
// col = wn*64+nt*16+(lane&15). Same m89-verified C/D layout as old engine.
template <typename TO, bool BIAS, bool GELU>
__device__ __forceinline__ void epilogue256(const Acc256& acc, TO* __restrict__ C,
                                            int ldc, const float* __restrict__ bias,
                                            float scale) {
  int lane = threadIdx.x & 63;
  int wave = threadIdx.x >> 6;
  int wm = wave >> 2, wn = wave & 3;
  int rbase = wm * 128 + ((lane >> 4) << 2);
  int cbase = wn * 64 + (lane & 15);
#pragma unroll
  for (int mt = 0; mt < 8; ++mt) {
#pragma unroll
    for (int nt = 0; nt < 4; ++nt) {
      int nn = cbase + nt * 16;
      float bv = BIAS ? bias[nn] : 0.0f;
#pragma unroll
      for (int rr = 0; rr < 4; ++rr) {
        int mm = rbase + mt * 16 + rr;
        float c = acc.a[mt][nt][rr] * scale + bv;
        if (GELU) c = gelu_f(c);
        if constexpr (__hip_internal::is_same<TO, bf16>::value)
          C[(size_t)mm * ldc + nn] = f2b(c);
        else
          C[(size_t)mm * ldc + nn] = c;
      }
    }
  }
}

// ---------------------------------------------------------------------------
// Kernel 1a: Q,K projections (256^2 engine). grid (32,4,2): z=0->Q, z=1->K.
// ---------------------------------------------------------------------------
__global__ __launch_bounds__(512, 2) void k_qkv256(
    const bf16* __restrict__ X, const bf16* __restrict__ Wq,
    const bf16* __restrict__ Wk, const float* __restrict__ bq,
    const float* __restrict__ bk, bf16* __restrict__ Q,
    bf16* __restrict__ Ko) {
  __shared__ alignas(16) char arena[131072];
  const int K = 1024, N = 1024;
  int z = blockIdx.z;
  const bf16* W = z ? Wk : Wq;
  const float* bias = z ? bk : bq;
  const bf16* A = X + (size_t)blockIdx.x * 256 * K;
  const bf16* B = W + (size_t)blockIdx.y * 256 * K;
  Acc256 acc = {};
  gemm256_core(A, B, K, K, K, acc, arena);
  bf16* C = (z ? Ko : Q) + (size_t)blockIdx.x * 256 * N + blockIdx.y * 256;
  epilogue256<bf16, true, false>(acc, C, N, bias + blockIdx.y * 256, 1.0f);
}

// ---------------------------------------------------------------------------
// Kernel 1b: V projection, stored transposed Vt[b][d][s] (old engine +
// verified LDS-transpose epilogue). grid (64,8).
// ---------------------------------------------------------------------------
__global__ __launch_bounds__(256) void k_v(
    const bf16* __restrict__ X, const bf16* __restrict__ Wv,
    const float* __restrict__ bv, bf16* __restrict__ Vt) {
  __shared__ alignas(16) char arena[17408];  // 16KB GEMM | 17.4KB transpose
  bf16* sA = (bf16*)arena;
  bf16* sB = (bf16*)(arena + 8192);
  const int K = 1024;
  const bf16* A = X + (size_t)blockIdx.x * 128 * K;
  const bf16* B = Wv + (size_t)blockIdx.y * 128 * K;
  Acc acc = {};
  gemm_core(A, B, K, K, K, acc, sA, sB);

  bf16* sT = (bf16*)arena;  // 64 x 136 bf16 = 17408 B (GEMM arena dead)
  int tid = threadIdx.x;
  int lane = tid & 63;
  int wave = tid >> 6;
  int wm = wave & 1, wn = wave >> 1;
  int b  = blockIdx.x >> 4;               // batch
  int s0 = (blockIdx.x & 15) * 128;       // seq base within batch
#pragma unroll
  for (int p = 0; p < 2; ++p) {           // 64 d-rows per pass
    __syncthreads();
    if (wn == p) {
      int rloc_s = wm * 64 + ((lane >> 4) << 2);   // local token
#pragma unroll
      for (int tn = 0; tn < 4; ++tn) {
        int nl = (lane & 15) + tn * 16;            // local d within pass
        float bvv = bv[blockIdx.y * 128 + p * 64 + nl];
#pragma unroll
        for (int tm = 0; tm < 4; ++tm)
#pragma unroll
          for (int rr = 0; rr < 4; ++rr)
            sT[nl * 136 + rloc_s + tm * 16 + rr] =
                f2b(acc.a[tm][tn][rr] + bvv);
      }
    }
    __syncthreads();
    int c = tid & 15, r0 = tid >> 4;      // 16 col-chunks x 16 rows
#pragma unroll
    for (int j = 0; j < 4; ++j) {
      int rl = r0 + j * 16;               // local d row (0..63)
      int n = blockIdx.y * 128 + p * 64 + rl;
      *(bf16x8*)(Vt + ((size_t)b * 1024 + n) * 2048 + s0 + c * 8) =
          *(const bf16x8*)(sT + rl * 136 + c * 8);
    }
  }
}

// ---------------------------------------------------------------------------
// Kernel 2: scores = Q K^T / 32 per batch (256^2 engine — measured better
// than 128^2 despite 144-block grid: R2 454 vs R3 471). grid (8,8,4).
// bx descending; upper-triangle 256-tiles skipped.
// ---------------------------------------------------------------------------
__global__ __launch_bounds__(512, 2) void k_scores256(
    const bf16* __restrict__ Q, const bf16* __restrict__ Kk,
    bf16* __restrict__ P) {
  int bx = 7 - (int)blockIdx.x;
  if ((int)blockIdx.y > bx) return;  // fully masked tile (never read later)
  __shared__ alignas(16) char arena[131072];
  const int K = 1024, S = 2048;
  int z = blockIdx.z;
  const bf16* A = Q + (size_t)z * S * K + (size_t)bx * 256 * K;
  const bf16* B = Kk + (size_t)z * S * K + (size_t)blockIdx.y * 256 * K;
  Acc256 acc = {};
  gemm256_core(A, B, K, K, K, acc, arena);
  bf16* C = P + (size_t)z * S * S + (size_t)bx * 256 * S + blockIdx.y * 256;
  epilogue256<bf16, false, false>(acc, C, S, nullptr, 0.03125f);
}

// ---------------------------------------------------------------------------
// Kernel 3: causal softmax in-place on P rows. grid (2048,4). bf16x8
// vectorized; zeros masked tail up to next 128-multiple (k_attn's cap).
// (R4's stats-only + fused-attn variant measured +27us — full softmax kept.)
// ---------------------------------------------------------------------------
__global__ __launch_bounds__(256) void k_softmax(bf16* __restrict__ P) {
  const int S = 2048;
  int q = blockIdx.x, z = blockIdx.y;
  bf16* row = P + ((size_t)z * S + q) * S;
  __shared__ float red[4];
  int tid = threadIdx.x;
  int kcap = ((q >> 7) + 1) << 7;  // k_attn never reads past this
  int nch = kcap >> 3;             // 8-elem chunks (kcap % 8 == 0)

  float mx = -1e30f;
  for (int c = tid; c < nch; c += 256) {
    int k = c << 3;
    bf16x8 v = *(const bf16x8*)(row + k);
#pragma unroll
    for (int j = 0; j < 8; ++j)
      if (k + j <= q) mx = fmaxf(mx, bs2f(v[j]));
  }
#pragma unroll
  for (int o = 32; o > 0; o >>= 1) mx = fmaxf(mx, __shfl_xor(mx, o));
  if ((tid & 63) == 0) red[tid >> 6] = mx;
  __syncthreads();
  mx = fmaxf(fmaxf(red[0], red[1]), fmaxf(red[2], red[3]));
  __syncthreads();

  float sum = 0.0f;
  for (int c = tid; c < nch; c += 256) {
    int k = c << 3;
    bf16x8 v = *(const bf16x8*)(row + k);
#pragma unroll
    for (int j = 0; j < 8; ++j)
      if (k + j <= q) sum += __expf(bs2f(v[j]) - mx);
  }
#pragma unroll
  for (int o = 32; o > 0; o >>= 1) sum += __shfl_xor(sum, o);
  if ((tid & 63) == 0) red[tid >> 6] = sum;
  __syncthreads();
  sum = red[0] + red[1] + red[2] + red[3];
  float inv = 1.0f / sum;

  for (int c = tid; c < nch; c += 256) {
    int k = c << 3;
    bf16x8 v = *(const bf16x8*)(row + k);
    bf16 t[8];
#pragma unroll
    for (int j = 0; j < 8; ++j) {
      float p = (k + j <= q) ? __expf(bs2f(v[j]) - mx) * inv : 0.0f;
      t[j] = f2b(p);
    }
    *(bf16x8*)(row + k) = *(bf16x8*)t;
  }
}

// ---------------------------------------------------------------------------
// Kernel 4: attn = P @ V (B = Vt, K-major). grid (16,8,4). Triangular:
// K-loop stops at (bx+1)*128; bx remapped descending for load balance.
// (old engine: 256^2 tiles would give only 128 blocks -> half-GPU tail)
// ---------------------------------------------------------------------------
__global__ __launch_bounds__(256) void k_attn(const bf16* __restrict__ P,
                                              const bf16* __restrict__ Vt,
                                              bf16* __restrict__ O) {
  __shared__ alignas(16) char arena[16384];
  bf16* sA = (bf16*)arena;
  bf16* sB = (bf16*)(arena + 8192);
  const int S = 2048, D = 1024;
  int bx = 15 - (int)blockIdx.x;
  int z = blockIdx.z;
  int Keff = (bx + 1) * 128;
  const bf16* A = P  + (size_t)z * S * S + (size_t)bx * 128 * S;
  const bf16* B = Vt + (size_t)z * D * S + (size_t)blockIdx.y * 128 * S;
  Acc acc = {};
  gemm_core(A, B, Keff, S, S, acc, sA, sB);
  bf16* C = O + (size_t)z * S * D + (size_t)bx * 128 * D + blockIdx.y * 128;
  epilogue<bf16, false, false>(acc, C, D, nullptr, 1.0f);
}

// ---------------------------------------------------------------------------
// Kernel 5: out = attn @ Wo^T + bo (Wob bf16). grid (64,8). (old engine:
// 256^2 would give 128 blocks -> half-GPU)
// ---------------------------------------------------------------------------
__global__ __launch_bounds__(256) void k_out(const bf16* __restrict__ A0,
                                             const bf16* __restrict__ W,
                                             const float* __restrict__ bias,
                                             bf16* __restrict__ C0) {
  __shared__ alignas(16) char arena[16384];
  bf16* sA = (bf16*)arena;
  bf16* sB = (bf16*)(arena + 8192);
  const int K = 1024, N = 1024;
  const bf16* A = A0 + (size_t)blockIdx.x * 128 * K;
  const bf16* B = W + (size_t)blockIdx.y * 128 * K;
  Acc acc = {};
  gemm_core(A, B, K, K, K, acc, sA, sB);
  bf16* C = C0 + (size_t)blockIdx.x * 128 * N + blockIdx.y * 128;
  epilogue<bf16, true, false>(acc, C, N, bias + blockIdx.y * 128, 1.0f);
}

// ---------------------------------------------------------------------------
// Kernel 6: ff = GELU(out @ Wf^T + bf) -> f32 d_out (256^2 engine).
// grid (32,16) = 512 blocks = 2 perfectly balanced rounds on 256 CUs.
// ---------------------------------------------------------------------------
__global__ __launch_bounds__(512, 2) void k_ffn256(
    const bf16* __restrict__ A0, const bf16* __restrict__ W,
    const float* __restrict__ bias, float* __restrict__ C0) {
  __shared__ alignas(16) char arena[131072];
  const int K = 1024, N = 4096;
  const bf16* A = A0 + (size_t)blockIdx.x * 256 * K;
  const bf16* B = W + (size_t)blockIdx.y * 256 * K;
  Acc256 acc = {};
  gemm256_core(A, B, K, K, K, acc, arena);
  float* C = C0 + (size_t)blockIdx.x * 256 * N + blockIdx.y * 256;
  epilogue256<float, true, true>(acc, C, N, bias + blockIdx.y * 256, 1.0f);
}

// ---------------------------------------------------------------------------
// Workspace (80 MB), liveness-based reuse across the 5 x 16MB regions:
//   A [0,16):   xb (conv -> qkv)        | then P[0:16M)   (scores..attn)
//   B [16,32):  Wqb,Wkb,Wvb (6MB)       | then P[16M:32M)
//   C [32,48):  Q  (qkv -> scores)      | then attn (attn -> out)
//   D [48,64):  K  (qkv -> scores)      | then Wob(2MB)+Wfb(8MB)
//   E [64,80):  Vt (qkv -> attn)        | then out (out -> ffn)
// ---------------------------------------------------------------------------
extern "C" void kernel_launch(void* const* d_in, const int* in_sizes, int n_in,
                              void* d_out, int out_size, void* d_ws,
                              size_t ws_size, hipStream_t stream) {
  const float* x   = (const float*)d_in[0];
  const float* Wq  = (const float*)d_in[1];
  const float* bq  = (const float*)d_in[2];
  const float* Wk  = (const float*)d_in[3];
  const float* bk  = (const float*)d_in[4];
  const float* Wv  = (const float*)d_in[5];
  const float* bv  = (const float*)d_in[6];
  const float* Wo  = (const float*)d_in[7];
  const float* bo  = (const float*)d_in[8];
  const float* Wf  = (const float*)d_in[9];
  const float* bfb = (const float*)d_in[10];

  char* ws = (char*)d_ws;
  const size_t MB = 1 << 20;
  bf16* xb   = (bf16*)(ws);                  // A
  bf16* Wqb  = (bf16*)(ws + 16 * MB);        // B
  bf16* Wkb  = (bf16*)(ws + 18 * MB);
  bf16* Wvb  = (bf16*)(ws + 20 * MB);
  bf16* P    = (bf16*)(ws);                  // A+B after qkv
  bf16* Q    = (bf16*)(ws + 32 * MB);        // C
  bf16* Kb   = (bf16*)(ws + 48 * MB);        // D
  bf16* Wob  = (bf16*)(ws + 48 * MB);        // D after scores
  bf16* Wfb  = (bf16*)(ws + 50 * MB);
  bf16* Vt   = (bf16*)(ws + 64 * MB);        // E
  bf16* attn = Q;                            // C after scores
  bf16* out  = Vt;                           // E after attn
  float* y   = (float*)d_out;

  k_conv4<<<11264, 256, 0, stream>>>(x, Wq, Wk, Wv, xb, Wqb, Wkb, Wvb);
  k_qkv256<<<dim3(32, 4, 2), 512, 0, stream>>>(xb, Wqb, Wkb, bq, bk, Q, Kb);
  k_v<<<dim3(64, 8), 256, 0, stream>>>(xb, Wvb, bv, Vt);
  k_scores256<<<dim3(8, 8, 4), 512, 0, stream>>>(Q, Kb, P);
  k_conv2<<<5120, 256, 0, stream>>>(Wo, Wf, Wob, Wfb);
  k_softmax<<<dim3(2048, 4), 256, 0, stream>>>(P);
  k_attn<<<dim3(16, 8, 4), 256, 0, stream>>>(P, Vt, attn);
  k_out<<<dim3(64, 8), 256, 0, stream>>>(attn, Wob, bo, out);
  k_ffn256<<<dim3(32, 16), 512, 0, stream>>>(out, Wfb, bfb, y);
}